// Round 2
// baseline (422.702 us; speedup 1.0000x reference)
//
#include <hip/hip_runtime.h>

typedef __bf16 bf16;
typedef __bf16 bf16x8 __attribute__((ext_vector_type(8)));
typedef float  f32x4  __attribute__((ext_vector_type(4)));

// Problem constants
#define NSPEC   512          // 256 pairs * 2
#define BOUT    9999         // GROUPS*3
#define K0A     10240        // BOUT padded to 16*10*64 (ksplit*kiters*BK)
#define N00     1024         // 1000 padded
#define KSPLIT0 16
#define NBLK    512          // encoder_fused grid: 2 blocks/CU x 256 CUs, exactly co-resident

// async global->LDS, 16B per lane; lds base must be wave-uniform (HW adds lane*16)
__device__ __forceinline__ void gload_lds16(const bf16* g, bf16* l) {
    auto* gp = reinterpret_cast<const __attribute__((address_space(1))) unsigned int*>(
        reinterpret_cast<uintptr_t>(g));
    auto* lp = reinterpret_cast<__attribute__((address_space(3))) unsigned int*>(
        reinterpret_cast<uintptr_t>(l));
    __builtin_amdgcn_global_load_lds(gp, lp, 16, 0, 0);
}

// Manual grid barrier (graph-capture-safe; no cooperative launch).
// Each sync point uses its OWN counter (no reset/reuse race); prep_all zeroes them
// each launch, ordered before encoder_fused by the dispatch boundary.
// __threadfence() = agent-scope fence: buffer_wbl2 (release, cross-XCD L2 writeback)
// / buffer_inv (acquire) — required because per-XCD L2s are not coherent.
__device__ __forceinline__ void grid_barrier(unsigned* bar) {
    __syncthreads();                       // all block threads done; vmcnt drained
    if (threadIdx.x == 0) {
        __threadfence();                   // release: publish this block's writes
        __hip_atomic_fetch_add(bar, 1u, __ATOMIC_ACQ_REL, __HIP_MEMORY_SCOPE_AGENT);
        while (__hip_atomic_load(bar, __ATOMIC_RELAXED, __HIP_MEMORY_SCOPE_AGENT) < NBLK)
            __builtin_amdgcn_s_sleep(8);
        __threadfence();                   // acquire: invalidate stale L1/L2 lines
    }
    __syncthreads();                       // rest of block waits on thread 0's spin
}

// ---------------- transpose helper: 64(n) x 32(k) tile, 512 threads ----------------
__device__ __forceinline__ void transpose_tile64(const float* __restrict__ src,
                                                 bf16* __restrict__ dst,
                                                 int K, int N, int K0,
                                                 float* tile, int bx, int by) {
    int n0 = bx * 64, k0 = by * 32;
    int t = threadIdx.x;
    {
        int kr = t >> 4, nc = (t & 15) * 4;          // 32 rows x 64 cols
        int gk = k0 + kr;
#pragma unroll
        for (int e = 0; e < 4; ++e) {
            int gn = n0 + nc + e;
            tile[kr * 65 + nc + e] = (gk < K && gn < N) ? src[(size_t)gk * N + gn] : 0.0f;
        }
    }
    __syncthreads();
    {
        int nr = t >> 3, kc = (t & 7) * 4;           // 64 n-rows x 32 k-cols
        bf16 v[4];
#pragma unroll
        for (int e = 0; e < 4; ++e) v[e] = (bf16)tile[(kc + e) * 65 + nr];
        *(ushort4*)&dst[(size_t)(n0 + nr) * K0 + k0 + kc] = *(ushort4*)v;
    }
}

// ---------------- mega-prep: weight transposes + build_A + zero pads + zero psums/bars ----------------
__global__ __launch_bounds__(512) void prep_all(const float* __restrict__ mz,
                                                const float* __restrict__ inten,
                                                const float* __restrict__ bw,
                                                const float* __restrict__ bb,
                                                const float* __restrict__ w0,
                                                const float* __restrict__ w1,
                                                const float* __restrict__ w2,
                                                const float* __restrict__ we,
                                                bf16* __restrict__ A,
                                                bf16* __restrict__ B0t,
                                                bf16* __restrict__ B1t,
                                                bf16* __restrict__ B2t,
                                                bf16* __restrict__ BEt,
                                                bf16* __restrict__ H1b,
                                                bf16* __restrict__ H2b,
                                                float* __restrict__ psums,
                                                unsigned* __restrict__ bars) {
    __shared__ float smem[K0A];    // 40 KB: sacc for build_A, tile[32*65] for transposes
    int b = blockIdx.x;
    if (b < 5120) {                       // w0 -> B0t (1024 x 10240): 16 x 320 tiles
        transpose_tile64(w0, B0t, BOUT, 1000, K0A, smem, b & 15, b >> 4);
    } else if (b < 5568) {                // w1 -> B1t (896 x 1024): 14 x 32
        int r = b - 5120;
        transpose_tile64(w1, B1t, 1000, 800, 1024, smem, r % 14, r / 14);
    } else if (b < 6016) {                // w2 -> B2t (896 x 1024): 14 x 32
        int r = b - 5568;
        transpose_tile64(w2, B2t, 800, 800, 1024, smem, r % 14, r / 14);
    } else if (b < 6240) {                // we -> BEt (448 x 1024): 7 x 32
        int r = b - 6016;
        transpose_tile64(we, BEt, 800, 400, 1024, smem, r % 7, r / 7);
    } else if (b < 6752) {                // build_A: one block per spectrum
        const int spec = b - 6240;
        const int t = threadIdx.x;
#pragma unroll
        for (int i = 0; i < 5; ++i)
            *(float4*)&smem[(i * 512 + t) * 4] = float4{0.f, 0.f, 0.f, 0.f};
        __syncthreads();
        {
            float m = mz[(size_t)spec * 512 + t];
            float v = inten[(size_t)spec * 512 + t];
            bool mask = (m >= 0.0f) && (m < 1000.0f);
            int idx = (int)(m / 0.01f);       // IEEE div + trunc, matches astype(int32)
            idx = min(max(idx, 0), 99999);
            if (mask && idx < 99990) {
                int g = idx / 30;
                float val = sqrtf(v);         // inten ** 0.5
                const float* w = bw + (size_t)idx * 3;
                atomicAdd(&smem[g * 3 + 0], val * w[0]);
                atomicAdd(&smem[g * 3 + 1], val * w[1]);
                atomicAdd(&smem[g * 3 + 2], val * w[2]);
            }
        }
        __syncthreads();
        bf16* Arow = A + (size_t)spec * K0A;
#pragma unroll
        for (int i = 0; i < 5; ++i) {
            int c = (i * 512 + t) * 4;
            float4 s = *(const float4*)&smem[c];
            bf16 o[4];
            o[0] = (bf16)((c + 0 < BOUT) ? bb[c + 0] + s.x : 0.f);
            o[1] = (bf16)((c + 1 < BOUT) ? bb[c + 1] + s.y : 0.f);
            o[2] = (bf16)((c + 2 < BOUT) ? bb[c + 2] + s.z : 0.f);
            o[3] = (bf16)((c + 3 < BOUT) ? bb[c + 3] + s.w : 0.f);
            *(ushort4*)&Arow[c] = *(ushort4*)o;
        }
    } else if (b < 6784) {                // zero K-pad cols 896..1023 of H1b/H2b
        int idx = b - 6752;               // 0..31
        bf16* H = (idx < 16) ? H1b : H2b;
        int sub = idx & 15;
        int t = threadIdx.x;
        int row = sub * 32 + (t >> 4);
        int col = 896 + (t & 15) * 8;
        *(uint4*)&H[(size_t)row * 1024 + col] = uint4{0u, 0u, 0u, 0u};
    } else {                              // zero cosine accumulators + grid-barrier counters
        for (int i = threadIdx.x; i < 768; i += 512) psums[i] = 0.f;
        if (threadIdx.x < 8) bars[threadIdx.x] = 0u;
    }
}

// ---------------- tail GEMM phase body: 32x32 tiles, BK=256, wave-split-K, dbuf, swizzled ----
template <bool LAST>
__device__ __forceinline__ void tail_phase(const bf16* __restrict__ A,
                                           const bf16* __restrict__ Bt,
                                           const float* __restrict__ bias,
                                           bf16* __restrict__ Ob,
                                           float* __restrict__ psums,
                                           int Nreal, int ntiles, int bid,
                                           bf16 (&As)[2][8192], bf16 (&Bs)[2][8192],
                                           f32x4 (&xacc)[4][64]) {
    constexpr int BK = 256, KITERS = 4;
    const int mt = bid / ntiles, nt = bid % ntiles;
    const int tid = threadIdx.x, wave = tid >> 6, lane = tid & 63;
    const int g = wave >> 2, w2 = wave & 3;
    const int wm = w2 & 1, wn = w2 >> 1;
    const int lrow = lane & 15, quad = lane >> 4;

    const bf16* Ag = A  + (size_t)(mt * 32) * 1024;
    const bf16* Bg = Bt + (size_t)(nt * 32) * 1024;

    auto stage = [&](int buf, int kk) {
        const int k = kk * BK;
#pragma unroll
        for (int j = 0; j < 2; ++j) {
            int row0 = (wave + j * 8) * 2;             // wave-uniform; covers rows row0, row0+1
            int row = row0 + (lane >> 5);
            int ch  = (lane & 31) ^ (row & 31);        // swizzled source chunk (32 chunks/row)
            gload_lds16(Ag + (size_t)row * 1024 + k + ch * 8, &As[buf][row0 * BK]);
            gload_lds16(Bg + (size_t)row * 1024 + k + ch * 8, &Bs[buf][row0 * BK]);
        }
    };

    f32x4 acc = {};
    stage(0, 0);
    for (int kk = 0; kk < KITERS; ++kk) {
        const int cur = kk & 1;
        __syncthreads();
        if (kk + 1 < KITERS) stage(cur ^ 1, kk + 1);
#pragma unroll
        for (int ks = 0; ks < 4; ++ks) {
            int ra = wm * 16 + lrow, rb = wn * 16 + lrow;
            int c = g * 16 + ks * 4 + quad;            // group g takes its k-half
            bf16x8 af  = *(const bf16x8*)&As[cur][ra * BK + ((c ^ (ra & 31)) << 3)];
            bf16x8 bfr = *(const bf16x8*)&Bs[cur][rb * BK + ((c ^ (rb & 31)) << 3)];
            acc = __builtin_amdgcn_mfma_f32_16x16x32_bf16(af, bfr, acc, 0, 0, 0);
        }
    }
    // combine the two k-halves
    __syncthreads();
    if (g == 1) xacc[w2][lane] = acc;
    __syncthreads();
    if (g == 0) {
        f32x4 o = xacc[w2][lane];
        acc[0] += o[0]; acc[1] += o[1]; acc[2] += o[2]; acc[3] += o[3];
        int row0 = mt * 32 + wm * 16 + quad * 4;
        int col  = nt * 32 + wn * 16 + lrow;
        if (!LAST) {
            float bv = (col < Nreal) ? bias[col] : 0.f;
#pragma unroll
            for (int r = 0; r < 4; ++r)
                Ob[(size_t)(row0 + r) * 1024 + col] = (bf16)fmaxf(acc[r] + bv, 0.f);
        } else {
            bool valid = (col < 400);
            float bv = valid ? bias[col] : 0.f;
            float v[4];
#pragma unroll
            for (int r = 0; r < 4; ++r) v[r] = valid ? (acc[r] + bv) : 0.f;
            int p0 = row0 >> 1;                        // pairs p0, p0+1 (row0 even)
            float sums[6] = {v[0] * v[1], v[0] * v[0], v[1] * v[1],
                             v[2] * v[3], v[2] * v[2], v[3] * v[3]};
#pragma unroll
            for (int off = 1; off < 16; off <<= 1)
#pragma unroll
                for (int s = 0; s < 6; ++s) sums[s] += __shfl_xor(sums[s], off);
            if (lrow == 0) {
#pragma unroll
                for (int s = 0; s < 3; ++s) {
                    atomicAdd(&psums[(p0 + 0) * 3 + s], sums[s]);
                    atomicAdd(&psums[(p0 + 1) * 3 + s], sums[3 + s]);
                }
            }
        }
    }
}

// ---------------- fused encoder: gemm0 -> reduce -> tail1 -> tail2 -> tail3 -> cosine ----------------
// One PLAIN dispatch (no cooperative API) with manual grid barriers. Co-residency is pinned:
// LDS 68 KB -> exactly 2 blocks/CU (136<=160 KB); __launch_bounds__(512,4) caps VGPR at 128
// -> 4 waves/SIMD fits the 2048-reg pool; 16 waves/CU <= 32. Grid 512 = 2 x 256 CUs.
__global__ __launch_bounds__(512, 4) void encoder_fused(const bf16* __restrict__ A,
                                                        const bf16* __restrict__ B0t,
                                                        bf16* __restrict__ Cslab,
                                                        const float* __restrict__ b0,
                                                        bf16* __restrict__ H0b,
                                                        const bf16* __restrict__ B1t,
                                                        const float* __restrict__ b1,
                                                        bf16* __restrict__ H1b,
                                                        const bf16* __restrict__ B2t,
                                                        const float* __restrict__ b2,
                                                        bf16* __restrict__ H2b,
                                                        const bf16* __restrict__ BEt,
                                                        const float* __restrict__ be,
                                                        float* __restrict__ psums,
                                                        unsigned* __restrict__ bars,
                                                        float* __restrict__ out) {
    __shared__ __align__(16) bf16 As[2][8192];   // 32 KB
    __shared__ __align__(16) bf16 Bs[2][8192];   // 32 KB
    __shared__ f32x4 xacc[4][64];                // 4 KB cross-wave combine (tail phases)
    const int bid = blockIdx.x;

    // ---- phase 0: GEMM0, 128x128xBK64, split-K=16 XCD-pinned, dbuf, swizzled (all 512 blocks)
    {
        constexpr int K0 = K0A, KITERS = 10, BK = 64;
        const int kp = bid & 15;                  // XCD = bid%8 hosts kp, kp+8 -> ~3.8 MB L2 footprint
        const int tile = bid >> 4;                // 0..31
        const int mt = tile & 3, nt = tile >> 2;  // 4 x 8
        const int tid = threadIdx.x, wave = tid >> 6, lane = tid & 63;
        const int wm = wave & 1, wn = wave >> 1;  // 2x4 wave grid: 64m x 32n per wave
        const int lrow = lane & 15, quad = lane >> 4;

        const bf16* Ag = A   + (size_t)(mt * 128) * K0 + kp * (KITERS * BK);
        const bf16* Bg = B0t + (size_t)(nt * 128) * K0 + kp * (KITERS * BK);

        auto stage = [&](int buf, int kk) {
            const int k = kk * BK;
            const int lr = lane >> 3;
            const int lch = lane & 7;
#pragma unroll
            for (int j = 0; j < 2; ++j) {                  // A: 128 rows in 2 calls/wave
                int row0 = j * 64 + wave * 8;
                int row = row0 + lr;
                int ch  = lch ^ (row & 7);
                gload_lds16(Ag + (size_t)row * K0 + k + ch * 8, &As[buf][row0 * BK]);
            }
#pragma unroll
            for (int j = 0; j < 2; ++j) {                  // B: 128 rows in 2 calls/wave
                int row0 = j * 64 + wave * 8;
                int row = row0 + lr;
                int ch  = lch ^ (row & 7);
                gload_lds16(Bg + (size_t)row * K0 + k + ch * 8, &Bs[buf][row0 * BK]);
            }
        };

        f32x4 acc[4][2] = {};
        stage(0, 0);
        for (int kk = 0; kk < KITERS; ++kk) {
            const int cur = kk & 1;
            __syncthreads();                      // buf[cur] drained (vmcnt0 at barrier)
            if (kk + 1 < KITERS) stage(cur ^ 1, kk + 1);
#pragma unroll
            for (int ks = 0; ks < 2; ++ks) {
                bf16x8 af[4], bfr[2];
                const int c = ks * 4 + quad;
#pragma unroll
                for (int im = 0; im < 4; ++im) {
                    int r = wm * 64 + im * 16 + lrow;
                    af[im] = *(const bf16x8*)&As[cur][r * BK + ((c ^ (r & 7)) << 3)];
                }
#pragma unroll
                for (int in = 0; in < 2; ++in) {
                    int r = wn * 32 + in * 16 + lrow;
                    bfr[in] = *(const bf16x8*)&Bs[cur][r * BK + ((c ^ (r & 7)) << 3)];
                }
#pragma unroll
                for (int im = 0; im < 4; ++im)
#pragma unroll
                    for (int in = 0; in < 2; ++in)
                        acc[im][in] = __builtin_amdgcn_mfma_f32_16x16x32_bf16(af[im], bfr[in], acc[im][in], 0, 0, 0);
            }
        }
        // bf16 partial stores into this kp's slab — no atomics
        bf16* C = Cslab + (size_t)kp * (NSPEC * N00);
#pragma unroll
        for (int im = 0; im < 4; ++im) {
            int row0 = mt * 128 + wm * 64 + im * 16 + quad * 4;
#pragma unroll
            for (int in = 0; in < 2; ++in) {
                int col = nt * 128 + wn * 32 + in * 16 + lrow;
#pragma unroll
                for (int r = 0; r < 4; ++r)
                    C[(size_t)(row0 + r) * N00 + col] = (bf16)acc[im][in][r];
            }
        }
    }
    grid_barrier(bars + 0);

    // ---- phase 1: reduce 16 bf16 slabs + bias + relu + bf16 cvt (65536 jobs of 8 elems)
    {
        int idx = bid * 512 + threadIdx.x;
        if (idx < 65536) {
            int r = idx >> 7, c = (idx & 127) * 8;
            float s[8] = {};
#pragma unroll
            for (int kp = 0; kp < KSPLIT0; ++kp) {
                bf16x8 v = *(const bf16x8*)&Cslab[(size_t)kp * (NSPEC * N00) + (size_t)r * N00 + c];
#pragma unroll
                for (int j = 0; j < 8; ++j) s[j] += (float)v[j];
            }
            bf16 o[8];
#pragma unroll
            for (int j = 0; j < 8; ++j)
                o[j] = (bf16)fmaxf(s[j] + ((c + j < 1000) ? b0[c + j] : 0.f), 0.f);
            *(uint4*)&H0b[(size_t)r * N00 + c] = *(uint4*)o;
        }
    }
    grid_barrier(bars + 1);

    // ---- phase 2: tail GEMM 1 (H0b @ B1t -> H1b), 448 active blocks
    if (bid < 448) tail_phase<false>(H0b, B1t, b1, H1b, nullptr, 800, 28, bid, As, Bs, xacc);
    grid_barrier(bars + 2);

    // ---- phase 3: tail GEMM 2 (H1b @ B2t -> H2b)
    if (bid < 448) tail_phase<false>(H1b, B2t, b2, H2b, nullptr, 800, 28, bid, As, Bs, xacc);
    grid_barrier(bars + 3);

    // ---- phase 4: last GEMM + cosine partials (device-scope atomics)
    if (bid < 224) tail_phase<true>(H2b, BEt, be, nullptr, psums, 400, 14, bid, As, Bs, xacc);
    grid_barrier(bars + 4);

    // ---- phase 5: finalize cosine
    if (bid == 0 && threadIdx.x < 256) {
        int t = threadIdx.x;
        float d  = psums[t * 3 + 0];
        float s1 = psums[t * 3 + 1];
        float s2 = psums[t * 3 + 2];
        float n1 = fmaxf(sqrtf(s1), 1e-6f);
        float n2 = fmaxf(sqrtf(s2), 1e-6f);
        out[t] = d / (n1 * n2);
    }
}

extern "C" void kernel_launch(void* const* d_in, const int* in_sizes, int n_in,
                              void* d_out, int out_size, void* d_ws, size_t ws_size,
                              hipStream_t stream) {
    const float* mz    = (const float*)d_in[0];
    const float* inten = (const float*)d_in[1];
    const float* bw    = (const float*)d_in[2];
    const float* bb    = (const float*)d_in[3];
    const float* w0    = (const float*)d_in[4];
    const float* b0    = (const float*)d_in[5];
    const float* w1    = (const float*)d_in[6];
    const float* b1    = (const float*)d_in[7];
    const float* w2    = (const float*)d_in[8];
    const float* b2    = (const float*)d_in[9];
    const float* we    = (const float*)d_in[10];
    const float* be    = (const float*)d_in[11];
    float* out = (float*)d_out;

    char* ws = (char*)d_ws;
    size_t off = 0;
    auto alloc = [&](size_t bytes) { char* p = ws + off; off += (bytes + 255) & ~(size_t)255; return p; };
    bf16*  A     = (bf16*) alloc((size_t)NSPEC * K0A * 2);
    bf16*  B0t   = (bf16*) alloc((size_t)N00 * K0A * 2);
    bf16*  B1t   = (bf16*) alloc((size_t)896 * 1024 * 2);
    bf16*  B2t   = (bf16*) alloc((size_t)896 * 1024 * 2);
    bf16*  BEt   = (bf16*) alloc((size_t)448 * 1024 * 2);
    bf16*  Cslab = (bf16*) alloc((size_t)KSPLIT0 * NSPEC * N00 * 2);   // 16 MB
    bf16*  H0b   = (bf16*) alloc((size_t)NSPEC * 1024 * 2);
    bf16*  H1b   = (bf16*) alloc((size_t)NSPEC * 1024 * 2);
    bf16*  H2b   = (bf16*) alloc((size_t)NSPEC * 1024 * 2);
    float* psums = (float*)alloc(768 * 4);
    unsigned* bars = (unsigned*)alloc(8 * 4);

    // 1: weight transposes + build_A + zero pads + zero psums/barrier counters
    prep_all<<<6785, 512, 0, stream>>>(mz, inten, bw, bb, w0, w1, w2, we,
                                       A, B0t, B1t, B2t, BEt, H1b, H2b, psums, bars);
    // 2: everything else in ONE plain dispatch; manual grid barriers between phases
    encoder_fused<<<NBLK, 512, 0, stream>>>(A, B0t, Cslab, b0, H0b,
                                            B1t, b1, H1b,
                                            B2t, b2, H2b,
                                            BEt, be, psums, bars, out);
}

// Round 3
// 245.643 us; speedup vs baseline: 1.7208x; 1.7208x over previous
//
#include <hip/hip_runtime.h>

typedef __bf16 bf16;
typedef __bf16 bf16x2 __attribute__((ext_vector_type(2)));
typedef __bf16 bf16x8 __attribute__((ext_vector_type(8)));
typedef float  f32x4  __attribute__((ext_vector_type(4)));

// Problem constants
#define NSPEC   512          // 256 pairs * 2
#define BOUT    9999         // GROUPS*3
#define K0A     10240        // BOUT padded to 16*10*64 (ksplit*kiters*BK)
#define N00     1024         // 1000 padded
#define KSPLIT0 16
#define NBLK    512          // encoder_fused grid: 2 blocks/CU x 256 CUs, exactly co-resident

// Barrier region layout: 5 barriers x 10 slots x 32 dwords (128 B apart).
// slots 0..7 = per-group arrive counters (bid&7), slot 8 = master, slot 9 = release flag.
#define BAR_STRIDE 32
#define BAR_SLOTS  10
#define BAR_DWORDS (5 * BAR_SLOTS * BAR_STRIDE)   // 1600 dwords = 6.4 KB

// async global->LDS, 16B per lane; lds base must be wave-uniform (HW adds lane*16)
__device__ __forceinline__ void gload_lds16(const bf16* g, bf16* l) {
    auto* gp = reinterpret_cast<const __attribute__((address_space(1))) unsigned int*>(
        reinterpret_cast<uintptr_t>(g));
    auto* lp = reinterpret_cast<__attribute__((address_space(3))) unsigned int*>(
        reinterpret_cast<uintptr_t>(l));
    __builtin_amdgcn_global_load_lds(gp, lp, 16, 0, 0);
}

// Manual grid barrier, contention-free design (R2 post-mortem: single-line counter+poll
// cost ~55us/barrier from fabric serialization of 512 RMWs behind 512 device-scope polls).
//  - arrivals: 8 group counters on distinct 128B lines -> parallel RMW streams
//  - release: write-once flag on its own line; polling a read-only line doesn't
//    serialize against RMWs
//  - wait=false: arrive-and-exit blocks never poll at all
__device__ __forceinline__ void grid_barrier(unsigned* bars, int bi, unsigned nblk, bool wait) {
    __syncthreads();                       // block done with phase; LDS/vmem drained
    if (threadIdx.x == 0) {
        unsigned* base   = bars + bi * (BAR_SLOTS * BAR_STRIDE);
        unsigned* grp    = base + (blockIdx.x & 7) * BAR_STRIDE;
        unsigned* master = base + 8 * BAR_STRIDE;
        unsigned* flag   = base + 9 * BAR_STRIDE;
        __threadfence();                   // release: L2 writeback -> coherence point
        unsigned a = __hip_atomic_fetch_add(grp, 1u, __ATOMIC_RELAXED, __HIP_MEMORY_SCOPE_AGENT);
        if (a == (nblk >> 3) - 1u) {       // last arriver of this group
            unsigned m = __hip_atomic_fetch_add(master, 1u, __ATOMIC_RELAXED, __HIP_MEMORY_SCOPE_AGENT);
            if (m == 7u)                   // last group -> publish
                __hip_atomic_store(flag, 1u, __ATOMIC_RELEASE, __HIP_MEMORY_SCOPE_AGENT);
        }
        if (wait) {
            while (!__hip_atomic_load(flag, __ATOMIC_RELAXED, __HIP_MEMORY_SCOPE_AGENT))
                __builtin_amdgcn_s_sleep(2);
            __threadfence();               // acquire: invalidate stale L1/L2 lines
        }
    }
    __syncthreads();
}

// ---------------- transpose helper: 64(n) x 32(k) tile, 512 threads ----------------
__device__ __forceinline__ void transpose_tile64(const float* __restrict__ src,
                                                 bf16* __restrict__ dst,
                                                 int K, int N, int K0,
                                                 float* tile, int bx, int by) {
    int n0 = bx * 64, k0 = by * 32;
    int t = threadIdx.x;
    {
        int kr = t >> 4, nc = (t & 15) * 4;          // 32 rows x 64 cols
        int gk = k0 + kr;
#pragma unroll
        for (int e = 0; e < 4; ++e) {
            int gn = n0 + nc + e;
            tile[kr * 65 + nc + e] = (gk < K && gn < N) ? src[(size_t)gk * N + gn] : 0.0f;
        }
    }
    __syncthreads();
    {
        int nr = t >> 3, kc = (t & 7) * 4;           // 64 n-rows x 32 k-cols
        bf16 v[4];
#pragma unroll
        for (int e = 0; e < 4; ++e) v[e] = (bf16)tile[(kc + e) * 65 + nr];
        *(ushort4*)&dst[(size_t)(n0 + nr) * K0 + k0 + kc] = *(ushort4*)v;
    }
}

// ---------------- mega-prep: weight transposes + build_A + zero pads + zero psums/bars ----------------
__global__ __launch_bounds__(512) void prep_all(const float* __restrict__ mz,
                                                const float* __restrict__ inten,
                                                const float* __restrict__ bw,
                                                const float* __restrict__ bb,
                                                const float* __restrict__ w0,
                                                const float* __restrict__ w1,
                                                const float* __restrict__ w2,
                                                const float* __restrict__ we,
                                                bf16* __restrict__ A,
                                                bf16* __restrict__ B0t,
                                                bf16* __restrict__ B1t,
                                                bf16* __restrict__ B2t,
                                                bf16* __restrict__ BEt,
                                                bf16* __restrict__ H1b,
                                                bf16* __restrict__ H2b,
                                                float* __restrict__ psums,
                                                unsigned* __restrict__ bars) {
    __shared__ float smem[K0A];    // 40 KB: sacc for build_A, tile[32*65] for transposes
    int b = blockIdx.x;
    if (b < 5120) {                       // w0 -> B0t (1024 x 10240): 16 x 320 tiles
        transpose_tile64(w0, B0t, BOUT, 1000, K0A, smem, b & 15, b >> 4);
    } else if (b < 5568) {                // w1 -> B1t (896 x 1024): 14 x 32
        int r = b - 5120;
        transpose_tile64(w1, B1t, 1000, 800, 1024, smem, r % 14, r / 14);
    } else if (b < 6016) {                // w2 -> B2t (896 x 1024): 14 x 32
        int r = b - 5568;
        transpose_tile64(w2, B2t, 800, 800, 1024, smem, r % 14, r / 14);
    } else if (b < 6240) {                // we -> BEt (448 x 1024): 7 x 32
        int r = b - 6016;
        transpose_tile64(we, BEt, 800, 400, 1024, smem, r % 7, r / 7);
    } else if (b < 6752) {                // build_A: one block per spectrum
        const int spec = b - 6240;
        const int t = threadIdx.x;
#pragma unroll
        for (int i = 0; i < 5; ++i)
            *(float4*)&smem[(i * 512 + t) * 4] = float4{0.f, 0.f, 0.f, 0.f};
        __syncthreads();
        {
            float m = mz[(size_t)spec * 512 + t];
            float v = inten[(size_t)spec * 512 + t];
            bool mask = (m >= 0.0f) && (m < 1000.0f);
            int idx = (int)(m / 0.01f);       // IEEE div + trunc, matches astype(int32)
            idx = min(max(idx, 0), 99999);
            if (mask && idx < 99990) {
                int g = idx / 30;
                float val = sqrtf(v);         // inten ** 0.5
                const float* w = bw + (size_t)idx * 3;
                atomicAdd(&smem[g * 3 + 0], val * w[0]);
                atomicAdd(&smem[g * 3 + 1], val * w[1]);
                atomicAdd(&smem[g * 3 + 2], val * w[2]);
            }
        }
        __syncthreads();
        bf16* Arow = A + (size_t)spec * K0A;
#pragma unroll
        for (int i = 0; i < 5; ++i) {
            int c = (i * 512 + t) * 4;
            float4 s = *(const float4*)&smem[c];
            bf16 o[4];
            o[0] = (bf16)((c + 0 < BOUT) ? bb[c + 0] + s.x : 0.f);
            o[1] = (bf16)((c + 1 < BOUT) ? bb[c + 1] + s.y : 0.f);
            o[2] = (bf16)((c + 2 < BOUT) ? bb[c + 2] + s.z : 0.f);
            o[3] = (bf16)((c + 3 < BOUT) ? bb[c + 3] + s.w : 0.f);
            *(ushort4*)&Arow[c] = *(ushort4*)o;
        }
    } else if (b < 6784) {                // zero K-pad cols 896..1023 of H1b/H2b
        int idx = b - 6752;               // 0..31
        bf16* H = (idx < 16) ? H1b : H2b;
        int sub = idx & 15;
        int t = threadIdx.x;
        int row = sub * 32 + (t >> 4);
        int col = 896 + (t & 15) * 8;
        *(uint4*)&H[(size_t)row * 1024 + col] = uint4{0u, 0u, 0u, 0u};
    } else {                              // zero cosine accumulators + grid-barrier region
        for (int i = threadIdx.x; i < 768; i += 512) psums[i] = 0.f;
        for (int i = threadIdx.x; i < BAR_DWORDS; i += 512) bars[i] = 0u;
    }
}

// ---------------- tail GEMM phase body: 32x32 tiles, BK=256, wave-split-K, dbuf, swizzled ----
template <bool LAST>
__device__ __forceinline__ void tail_phase(const bf16* __restrict__ A,
                                           const bf16* __restrict__ Bt,
                                           const float* __restrict__ bias,
                                           bf16* __restrict__ Ob,
                                           float* __restrict__ psums,
                                           int Nreal, int ntiles, int bid,
                                           bf16 (&As)[2][8192], bf16 (&Bs)[2][8192],
                                           f32x4 (&xacc)[4][64]) {
    constexpr int BK = 256, KITERS = 4;
    const int mt = bid / ntiles, nt = bid % ntiles;
    const int tid = threadIdx.x, wave = tid >> 6, lane = tid & 63;
    const int g = wave >> 2, w2 = wave & 3;
    const int wm = w2 & 1, wn = w2 >> 1;
    const int lrow = lane & 15, quad = lane >> 4;

    const bf16* Ag = A  + (size_t)(mt * 32) * 1024;
    const bf16* Bg = Bt + (size_t)(nt * 32) * 1024;

    auto stage = [&](int buf, int kk) {
        const int k = kk * BK;
#pragma unroll
        for (int j = 0; j < 2; ++j) {
            int row0 = (wave + j * 8) * 2;             // wave-uniform; covers rows row0, row0+1
            int row = row0 + (lane >> 5);
            int ch  = (lane & 31) ^ (row & 31);        // swizzled source chunk (32 chunks/row)
            gload_lds16(Ag + (size_t)row * 1024 + k + ch * 8, &As[buf][row0 * BK]);
            gload_lds16(Bg + (size_t)row * 1024 + k + ch * 8, &Bs[buf][row0 * BK]);
        }
    };

    f32x4 acc = {};
    stage(0, 0);
    for (int kk = 0; kk < KITERS; ++kk) {
        const int cur = kk & 1;
        __syncthreads();
        if (kk + 1 < KITERS) stage(cur ^ 1, kk + 1);
#pragma unroll
        for (int ks = 0; ks < 4; ++ks) {
            int ra = wm * 16 + lrow, rb = wn * 16 + lrow;
            int c = g * 16 + ks * 4 + quad;            // group g takes its k-half
            bf16x8 af  = *(const bf16x8*)&As[cur][ra * BK + ((c ^ (ra & 31)) << 3)];
            bf16x8 bfr = *(const bf16x8*)&Bs[cur][rb * BK + ((c ^ (rb & 31)) << 3)];
            acc = __builtin_amdgcn_mfma_f32_16x16x32_bf16(af, bfr, acc, 0, 0, 0);
        }
    }
    // combine the two k-halves
    __syncthreads();
    if (g == 1) xacc[w2][lane] = acc;
    __syncthreads();
    if (g == 0) {
        f32x4 o = xacc[w2][lane];
        acc[0] += o[0]; acc[1] += o[1]; acc[2] += o[2]; acc[3] += o[3];
        int row0 = mt * 32 + wm * 16 + quad * 4;
        int col  = nt * 32 + wn * 16 + lrow;
        if (!LAST) {
            float bv = (col < Nreal) ? bias[col] : 0.f;
#pragma unroll
            for (int r = 0; r < 4; ++r)
                Ob[(size_t)(row0 + r) * 1024 + col] = (bf16)fmaxf(acc[r] + bv, 0.f);
        } else {
            bool valid = (col < 400);
            float bv = valid ? bias[col] : 0.f;
            float v[4];
#pragma unroll
            for (int r = 0; r < 4; ++r) v[r] = valid ? (acc[r] + bv) : 0.f;
            int p0 = row0 >> 1;                        // pairs p0, p0+1 (row0 even)
            float sums[6] = {v[0] * v[1], v[0] * v[0], v[1] * v[1],
                             v[2] * v[3], v[2] * v[2], v[3] * v[3]};
#pragma unroll
            for (int off = 1; off < 16; off <<= 1)
#pragma unroll
                for (int s = 0; s < 6; ++s) sums[s] += __shfl_xor(sums[s], off);
            if (lrow == 0) {
#pragma unroll
                for (int s = 0; s < 3; ++s) {
                    atomicAdd(&psums[(p0 + 0) * 3 + s], sums[s]);
                    atomicAdd(&psums[(p0 + 1) * 3 + s], sums[3 + s]);
                }
            }
        }
    }
}

// ---------------- fused encoder: gemm0 -> reduce -> tail1 -> tail2 -> tail3 -> cosine ----------------
// One PLAIN dispatch with contention-free manual grid barriers. Co-residency pinned:
// LDS 68 KB -> exactly 2 blocks/CU (136<=160 KB); __launch_bounds__(512,4) caps VGPR at 128
// -> 4 waves/SIMD fits the 2048-reg pool; 16 waves/CU <= 32. Grid 512 = 2 x 256 CUs.
// Blocks arrive-and-exit once they have no further phases (reduces pollers per barrier).
__global__ __launch_bounds__(512, 4) void encoder_fused(const bf16* __restrict__ A,
                                                        const bf16* __restrict__ B0t,
                                                        bf16* __restrict__ Cslab,
                                                        const float* __restrict__ b0,
                                                        bf16* __restrict__ H0b,
                                                        const bf16* __restrict__ B1t,
                                                        const float* __restrict__ b1,
                                                        bf16* __restrict__ H1b,
                                                        const bf16* __restrict__ B2t,
                                                        const float* __restrict__ b2,
                                                        bf16* __restrict__ H2b,
                                                        const bf16* __restrict__ BEt,
                                                        const float* __restrict__ be,
                                                        float* __restrict__ psums,
                                                        unsigned* __restrict__ bars,
                                                        float* __restrict__ out) {
    __shared__ __align__(16) bf16 As[2][8192];   // 32 KB
    __shared__ __align__(16) bf16 Bs[2][8192];   // 32 KB
    __shared__ f32x4 xacc[4][64];                // 4 KB cross-wave combine (tail phases)
    const int bid = blockIdx.x;

    // ---- phase 0: GEMM0, 128x128xBK64, split-K=16 XCD-pinned, dbuf, swizzled (all 512 blocks)
    {
        constexpr int K0 = K0A, KITERS = 10, BK = 64;
        const int kp = bid & 15;                  // XCD = bid%8 hosts kp, kp+8 -> ~3.8 MB L2 footprint
        const int tile = bid >> 4;                // 0..31
        const int mt = tile & 3, nt = tile >> 2;  // 4 x 8
        const int tid = threadIdx.x, wave = tid >> 6, lane = tid & 63;
        const int wm = wave & 1, wn = wave >> 1;  // 2x4 wave grid: 64m x 32n per wave
        const int lrow = lane & 15, quad = lane >> 4;

        const bf16* Ag = A   + (size_t)(mt * 128) * K0 + kp * (KITERS * BK);
        const bf16* Bg = B0t + (size_t)(nt * 128) * K0 + kp * (KITERS * BK);

        auto stage = [&](int buf, int kk) {
            const int k = kk * BK;
            const int lr = lane >> 3;
            const int lch = lane & 7;
#pragma unroll
            for (int j = 0; j < 2; ++j) {                  // A: 128 rows in 2 calls/wave
                int row0 = j * 64 + wave * 8;
                int row = row0 + lr;
                int ch  = lch ^ (row & 7);
                gload_lds16(Ag + (size_t)row * K0 + k + ch * 8, &As[buf][row0 * BK]);
            }
#pragma unroll
            for (int j = 0; j < 2; ++j) {                  // B: 128 rows in 2 calls/wave
                int row0 = j * 64 + wave * 8;
                int row = row0 + lr;
                int ch  = lch ^ (row & 7);
                gload_lds16(Bg + (size_t)row * K0 + k + ch * 8, &Bs[buf][row0 * BK]);
            }
        };

        f32x4 acc[4][2] = {};
        stage(0, 0);
        for (int kk = 0; kk < KITERS; ++kk) {
            const int cur = kk & 1;
            __syncthreads();                      // buf[cur] drained (vmcnt0 at barrier)
            if (kk + 1 < KITERS) stage(cur ^ 1, kk + 1);
#pragma unroll
            for (int ks = 0; ks < 2; ++ks) {
                bf16x8 af[4], bfr[2];
                const int c = ks * 4 + quad;
#pragma unroll
                for (int im = 0; im < 4; ++im) {
                    int r = wm * 64 + im * 16 + lrow;
                    af[im] = *(const bf16x8*)&As[cur][r * BK + ((c ^ (r & 7)) << 3)];
                }
#pragma unroll
                for (int in = 0; in < 2; ++in) {
                    int r = wn * 32 + in * 16 + lrow;
                    bfr[in] = *(const bf16x8*)&Bs[cur][r * BK + ((c ^ (r & 7)) << 3)];
                }
#pragma unroll
                for (int im = 0; im < 4; ++im)
#pragma unroll
                    for (int in = 0; in < 2; ++in)
                        acc[im][in] = __builtin_amdgcn_mfma_f32_16x16x32_bf16(af[im], bfr[in], acc[im][in], 0, 0, 0);
            }
        }
        // bf16 partial stores into this kp's slab — no atomics
        bf16* C = Cslab + (size_t)kp * (NSPEC * N00);
#pragma unroll
        for (int im = 0; im < 4; ++im) {
            int row0 = mt * 128 + wm * 64 + im * 16 + quad * 4;
#pragma unroll
            for (int in = 0; in < 2; ++in) {
                int col = nt * 128 + wn * 32 + in * 16 + lrow;
#pragma unroll
                for (int r = 0; r < 4; ++r)
                    C[(size_t)(row0 + r) * N00 + col] = (bf16)acc[im][in][r];
            }
        }
    }
    grid_barrier(bars, 0, NBLK, true);

    // ---- phase 1: reduce 16 bf16 slabs + bias + relu + bf16 cvt
    // One row per block (512 rows), 2 elems per thread -> all CUs engaged.
    {
        int r = bid, c = threadIdx.x * 2;
        float s0 = 0.f, s1 = 0.f;
#pragma unroll
        for (int kp = 0; kp < KSPLIT0; ++kp) {
            bf16x2 v = *(const bf16x2*)&Cslab[(size_t)kp * (NSPEC * N00) + (size_t)r * N00 + c];
            s0 += (float)v[0]; s1 += (float)v[1];
        }
        bf16 o[2];
        o[0] = (bf16)fmaxf(s0 + ((c     < 1000) ? b0[c]     : 0.f), 0.f);
        o[1] = (bf16)fmaxf(s1 + ((c + 1 < 1000) ? b0[c + 1] : 0.f), 0.f);
        *(ushort2*)&H0b[(size_t)r * N00 + c] = *(ushort2*)o;
    }
    if (bid >= 448) { grid_barrier(bars, 1, NBLK, false); return; }   // arrive & exit
    grid_barrier(bars, 1, NBLK, true);

    // ---- phase 2: tail GEMM 1 (H0b @ B1t -> H1b), blocks 0..447
    tail_phase<false>(H0b, B1t, b1, H1b, nullptr, 800, 28, bid, As, Bs, xacc);
    grid_barrier(bars, 2, 448, true);

    // ---- phase 3: tail GEMM 2 (H1b @ B2t -> H2b), blocks 0..447
    tail_phase<false>(H1b, B2t, b2, H2b, nullptr, 800, 28, bid, As, Bs, xacc);
    if (bid >= 224) { grid_barrier(bars, 3, 448, false); return; }    // arrive & exit
    grid_barrier(bars, 3, 448, true);

    // ---- phase 4: last GEMM + cosine partials (device-scope atomics), blocks 0..223
    tail_phase<true>(H2b, BEt, be, nullptr, psums, 400, 14, bid, As, Bs, xacc);
    if (bid != 0) { grid_barrier(bars, 4, 224, false); return; }      // arrive & exit
    grid_barrier(bars, 4, 224, true);                                 // single poller

    // ---- phase 5: finalize cosine (block 0)
    if (threadIdx.x < 256) {
        int t = threadIdx.x;
        float d  = psums[t * 3 + 0];
        float s1 = psums[t * 3 + 1];
        float s2 = psums[t * 3 + 2];
        float n1 = fmaxf(sqrtf(s1), 1e-6f);
        float n2 = fmaxf(sqrtf(s2), 1e-6f);
        out[t] = d / (n1 * n2);
    }
}

extern "C" void kernel_launch(void* const* d_in, const int* in_sizes, int n_in,
                              void* d_out, int out_size, void* d_ws, size_t ws_size,
                              hipStream_t stream) {
    const float* mz    = (const float*)d_in[0];
    const float* inten = (const float*)d_in[1];
    const float* bw    = (const float*)d_in[2];
    const float* bb    = (const float*)d_in[3];
    const float* w0    = (const float*)d_in[4];
    const float* b0    = (const float*)d_in[5];
    const float* w1    = (const float*)d_in[6];
    const float* b1    = (const float*)d_in[7];
    const float* w2    = (const float*)d_in[8];
    const float* b2    = (const float*)d_in[9];
    const float* we    = (const float*)d_in[10];
    const float* be    = (const float*)d_in[11];
    float* out = (float*)d_out;

    char* ws = (char*)d_ws;
    size_t off = 0;
    auto alloc = [&](size_t bytes) { char* p = ws + off; off += (bytes + 255) & ~(size_t)255; return p; };
    bf16*  A     = (bf16*) alloc((size_t)NSPEC * K0A * 2);
    bf16*  B0t   = (bf16*) alloc((size_t)N00 * K0A * 2);
    bf16*  B1t   = (bf16*) alloc((size_t)896 * 1024 * 2);
    bf16*  B2t   = (bf16*) alloc((size_t)896 * 1024 * 2);
    bf16*  BEt   = (bf16*) alloc((size_t)448 * 1024 * 2);
    bf16*  Cslab = (bf16*) alloc((size_t)KSPLIT0 * NSPEC * N00 * 2);   // 16 MB
    bf16*  H0b   = (bf16*) alloc((size_t)NSPEC * 1024 * 2);
    bf16*  H1b   = (bf16*) alloc((size_t)NSPEC * 1024 * 2);
    bf16*  H2b   = (bf16*) alloc((size_t)NSPEC * 1024 * 2);
    float* psums = (float*)alloc(768 * 4);
    unsigned* bars = (unsigned*)alloc(BAR_DWORDS * 4);

    // 1: weight transposes + build_A + zero pads + zero psums/barrier region
    prep_all<<<6785, 512, 0, stream>>>(mz, inten, bw, bb, w0, w1, w2, we,
                                       A, B0t, B1t, B2t, BEt, H1b, H2b, psums, bars);
    // 2: everything else in ONE plain dispatch; contention-free grid barriers between phases
    encoder_fused<<<NBLK, 512, 0, stream>>>(A, B0t, Cslab, b0, H0b,
                                            B1t, b1, H1b,
                                            B2t, b2, H2b,
                                            BEt, be, psums, bars, out);
}

// Round 4
// 163.275 us; speedup vs baseline: 2.5889x; 1.5045x over previous
//
#include <hip/hip_runtime.h>

typedef __bf16 bf16;
typedef __bf16 bf16x8 __attribute__((ext_vector_type(8)));
typedef float  f32x4  __attribute__((ext_vector_type(4)));

// Problem constants
#define NSPEC   512          // 256 pairs * 2
#define BOUT    9999         // GROUPS*3
#define K0A     10240        // BOUT padded to 16*10*64 (ksplit*kiters*BK)
#define N00     1024         // 1000 padded
#define KSPLIT0 16

// async global->LDS, 16B per lane; lds base must be wave-uniform (HW adds lane*16)
__device__ __forceinline__ void gload_lds16(const bf16* g, bf16* l) {
    auto* gp = reinterpret_cast<const __attribute__((address_space(1))) unsigned int*>(
        reinterpret_cast<uintptr_t>(g));
    auto* lp = reinterpret_cast<__attribute__((address_space(3))) unsigned int*>(
        reinterpret_cast<uintptr_t>(l));
    __builtin_amdgcn_global_load_lds(gp, lp, 16, 0, 0);
}

// ---------------- transpose helper: 64(n) x 32(k) tile, 512 threads ----------------
// R4: interior threads load one coalesced float4 (16B) instead of 4 scalar 16B-strided
// loads. All weight matrices have N%4==0 so the fast path is 16B-aligned.
__device__ __forceinline__ void transpose_tile64(const float* __restrict__ src,
                                                 bf16* __restrict__ dst,
                                                 int K, int N, int K0,
                                                 float* tile, int bx, int by) {
    int n0 = bx * 64, k0 = by * 32;
    int t = threadIdx.x;
    {
        int kr = t >> 4, nc = (t & 15) * 4;          // 32 rows x 64 cols
        int gk = k0 + kr, gn = n0 + nc;
        float4 v;
        if (gk < K && gn + 3 < N) {                  // interior fast path
            v = *reinterpret_cast<const float4*>(src + (size_t)gk * N + gn);
        } else {                                     // edge tiles: guarded scalars
            v.x = (gk < K && gn + 0 < N) ? src[(size_t)gk * N + gn + 0] : 0.f;
            v.y = (gk < K && gn + 1 < N) ? src[(size_t)gk * N + gn + 1] : 0.f;
            v.z = (gk < K && gn + 2 < N) ? src[(size_t)gk * N + gn + 2] : 0.f;
            v.w = (gk < K && gn + 3 < N) ? src[(size_t)gk * N + gn + 3] : 0.f;
        }
        tile[kr * 65 + nc + 0] = v.x;                // stride 65: bank-spread verified
        tile[kr * 65 + nc + 1] = v.y;
        tile[kr * 65 + nc + 2] = v.z;
        tile[kr * 65 + nc + 3] = v.w;
    }
    __syncthreads();
    {
        int nr = t >> 3, kc = (t & 7) * 4;           // 64 n-rows x 32 k-cols
        bf16 v[4];
#pragma unroll
        for (int e = 0; e < 4; ++e) v[e] = (bf16)tile[(kc + e) * 65 + nr];
        *(ushort4*)&dst[(size_t)(n0 + nr) * K0 + k0 + kc] = *(ushort4*)v;
    }
}

// ---------------- mega-prep: weight transposes + build_A + zero pads + zero psums/done ----------------
__global__ __launch_bounds__(512) void prep_all(const float* __restrict__ mz,
                                                const float* __restrict__ inten,
                                                const float* __restrict__ bw,
                                                const float* __restrict__ bb,
                                                const float* __restrict__ w0,
                                                const float* __restrict__ w1,
                                                const float* __restrict__ w2,
                                                const float* __restrict__ we,
                                                bf16* __restrict__ A,
                                                bf16* __restrict__ B0t,
                                                bf16* __restrict__ B1t,
                                                bf16* __restrict__ B2t,
                                                bf16* __restrict__ BEt,
                                                bf16* __restrict__ H1b,
                                                bf16* __restrict__ H2b,
                                                float* __restrict__ psums) {
    __shared__ float smem[K0A];    // 40 KB: sacc for build_A, tile[32*65] for transposes
    int b = blockIdx.x;
    if (b < 5120) {                       // w0 -> B0t (1024 x 10240): 16 x 320 tiles
        transpose_tile64(w0, B0t, BOUT, 1000, K0A, smem, b & 15, b >> 4);
    } else if (b < 5568) {                // w1 -> B1t (896 x 1024): 14 x 32
        int r = b - 5120;
        transpose_tile64(w1, B1t, 1000, 800, 1024, smem, r % 14, r / 14);
    } else if (b < 6016) {                // w2 -> B2t (896 x 1024): 14 x 32
        int r = b - 5568;
        transpose_tile64(w2, B2t, 800, 800, 1024, smem, r % 14, r / 14);
    } else if (b < 6240) {                // we -> BEt (448 x 1024): 7 x 32
        int r = b - 6016;
        transpose_tile64(we, BEt, 800, 400, 1024, smem, r % 7, r / 7);
    } else if (b < 6752) {                // build_A: one block per spectrum
        const int spec = b - 6240;
        const int t = threadIdx.x;
#pragma unroll
        for (int i = 0; i < 5; ++i)
            *(float4*)&smem[(i * 512 + t) * 4] = float4{0.f, 0.f, 0.f, 0.f};
        __syncthreads();
        {
            float m = mz[(size_t)spec * 512 + t];
            float v = inten[(size_t)spec * 512 + t];
            bool mask = (m >= 0.0f) && (m < 1000.0f);
            int idx = (int)(m / 0.01f);       // IEEE div + trunc, matches astype(int32)
            idx = min(max(idx, 0), 99999);
            if (mask && idx < 99990) {
                int g = idx / 30;
                float val = sqrtf(v);         // inten ** 0.5
                const float* w = bw + (size_t)idx * 3;
                atomicAdd(&smem[g * 3 + 0], val * w[0]);
                atomicAdd(&smem[g * 3 + 1], val * w[1]);
                atomicAdd(&smem[g * 3 + 2], val * w[2]);
            }
        }
        __syncthreads();
        bf16* Arow = A + (size_t)spec * K0A;
#pragma unroll
        for (int i = 0; i < 5; ++i) {
            int c = (i * 512 + t) * 4;
            float4 s = *(const float4*)&smem[c];
            bf16 o[4];
            o[0] = (bf16)((c + 0 < BOUT) ? bb[c + 0] + s.x : 0.f);
            o[1] = (bf16)((c + 1 < BOUT) ? bb[c + 1] + s.y : 0.f);
            o[2] = (bf16)((c + 2 < BOUT) ? bb[c + 2] + s.z : 0.f);
            o[3] = (bf16)((c + 3 < BOUT) ? bb[c + 3] + s.w : 0.f);
            *(ushort4*)&Arow[c] = *(ushort4*)o;
        }
    } else if (b < 6784) {                // zero K-pad cols 896..1023 of H1b/H2b
        int idx = b - 6752;               // 0..31
        bf16* H = (idx < 16) ? H1b : H2b;
        int sub = idx & 15;
        int t = threadIdx.x;
        int row = sub * 32 + (t >> 4);
        int col = 896 + (t & 15) * 8;
        *(uint4*)&H[(size_t)row * 1024 + col] = uint4{0u, 0u, 0u, 0u};
    } else {                              // zero cosine accumulators + done counter (1024 dwords)
        for (int i = threadIdx.x; i < 1024; i += 512) psums[i] = 0.f;
    }
}

// ---------------- GEMM0: 128x128xBK64, 512 thr, split-K=16 XCD-pinned, dbuf, swizzled, bf16 slabs ----
__global__ __launch_bounds__(512) void gemm0_splitk(const bf16* __restrict__ A,
                                                    const bf16* __restrict__ Bt,
                                                    bf16* __restrict__ Cslab) {
    constexpr int K0 = K0A, KITERS = 10, BK = 64;
    __shared__ __align__(16) bf16 As[2][128 * BK];   // 16 KB each buf
    __shared__ __align__(16) bf16 Bs[2][128 * BK];   // 16 KB each buf
    const int bid = blockIdx.x;
    const int kp = bid & 15;                  // XCD = bid%8 hosts kp, kp+8 -> ~3.8 MB L2 footprint
    const int tile = bid >> 4;                // 0..31
    const int mt = tile & 3, nt = tile >> 2;  // 4 x 8
    const int tid = threadIdx.x, wave = tid >> 6, lane = tid & 63;
    const int wm = wave & 1, wn = wave >> 1;  // 2x4 wave grid: 64m x 32n per wave
    const int lrow = lane & 15, quad = lane >> 4;

    const bf16* Ag = A  + (size_t)(mt * 128) * K0 + kp * (KITERS * BK);
    const bf16* Bg = Bt + (size_t)(nt * 128) * K0 + kp * (KITERS * BK);

    auto stage = [&](int buf, int kk) {
        const int k = kk * BK;
        const int lr = lane >> 3;                      // lane's row within an 8-row group
        const int lch = lane & 7;
#pragma unroll
        for (int j = 0; j < 2; ++j) {                  // A: 128 rows in 2 calls/wave (8 rows/call)
            int row0 = j * 64 + wave * 8;
            int row = row0 + lr;
            int ch  = lch ^ (row & 7);
            gload_lds16(Ag + (size_t)row * K0 + k + ch * 8, &As[buf][row0 * BK]);
        }
#pragma unroll
        for (int j = 0; j < 2; ++j) {                  // B: 128 rows in 2 calls/wave
            int row0 = j * 64 + wave * 8;
            int row = row0 + lr;
            int ch  = lch ^ (row & 7);
            gload_lds16(Bg + (size_t)row * K0 + k + ch * 8, &Bs[buf][row0 * BK]);
        }
    };

    f32x4 acc[4][2] = {};
    stage(0, 0);
    for (int kk = 0; kk < KITERS; ++kk) {
        const int cur = kk & 1;
        __syncthreads();                      // buf[cur] drained (vmcnt0 at barrier)
        if (kk + 1 < KITERS) stage(cur ^ 1, kk + 1);  // prefetch overlaps compute
#pragma unroll
        for (int ks = 0; ks < 2; ++ks) {
            bf16x8 af[4], bfr[2];
            const int c = ks * 4 + quad;
#pragma unroll
            for (int im = 0; im < 4; ++im) {
                int r = wm * 64 + im * 16 + lrow;
                af[im] = *(const bf16x8*)&As[cur][r * BK + ((c ^ (r & 7)) << 3)];
            }
#pragma unroll
            for (int in = 0; in < 2; ++in) {
                int r = wn * 32 + in * 16 + lrow;
                bfr[in] = *(const bf16x8*)&Bs[cur][r * BK + ((c ^ (r & 7)) << 3)];
            }
#pragma unroll
            for (int im = 0; im < 4; ++im)
#pragma unroll
                for (int in = 0; in < 2; ++in)
                    acc[im][in] = __builtin_amdgcn_mfma_f32_16x16x32_bf16(af[im], bfr[in], acc[im][in], 0, 0, 0);
        }
    }
    // bf16 partial stores into this kp's slab — no atomics, no fences
    bf16* C = Cslab + (size_t)kp * (NSPEC * N00);
#pragma unroll
    for (int im = 0; im < 4; ++im) {
        int row0 = mt * 128 + wm * 64 + im * 16 + quad * 4;
#pragma unroll
        for (int in = 0; in < 2; ++in) {
            int col = nt * 128 + wn * 32 + in * 16 + lrow;
#pragma unroll
            for (int r = 0; r < 4; ++r)
                C[(size_t)(row0 + r) * N00 + col] = (bf16)acc[im][in][r];
        }
    }
}

// ---------------- reduce 16 bf16 slabs + bias + relu + bf16 cvt ----------------
__global__ __launch_bounds__(256) void reduce_bias_relu(const bf16* __restrict__ Cslab,
                                                        const float* __restrict__ b0,
                                                        bf16* __restrict__ H0b) {
    int idx = blockIdx.x * 256 + threadIdx.x;     // 65536 chunks of 8
    int r = idx >> 7, c = (idx & 127) * 8;
    float s[8] = {};
#pragma unroll
    for (int kp = 0; kp < KSPLIT0; ++kp) {
        bf16x8 v = *(const bf16x8*)&Cslab[(size_t)kp * (NSPEC * N00) + (size_t)r * N00 + c];
#pragma unroll
        for (int j = 0; j < 8; ++j) s[j] += (float)v[j];
    }
    bf16 o[8];
#pragma unroll
    for (int j = 0; j < 8; ++j)
        o[j] = (bf16)fmaxf(s[j] + ((c + j < 1000) ? b0[c + j] : 0.f), 0.f);
    *(uint4*)&H0b[(size_t)r * N00 + c] = *(uint4*)o;
}

// ---------------- tail GEMM: 32x32 tiles, 512 thr, BK=256, wave-split-K, dbuf, swizzled ----------------
// LAST=true additionally finalizes the cosine: the last block to finish (done counter
// == 223) acquires and computes out[] — saves the cosine_fin dispatch.
template <bool LAST>
__global__ __launch_bounds__(512) void gemm_tail(const bf16* __restrict__ A,
                                                 const bf16* __restrict__ Bt,
                                                 const float* __restrict__ bias,
                                                 bf16* __restrict__ Ob,
                                                 float* __restrict__ psums,
                                                 unsigned* __restrict__ done,
                                                 float* __restrict__ out,
                                                 int Nreal, int ntiles) {
    constexpr int BK = 256, KITERS = 4;
    __shared__ __align__(16) bf16 As[2][32 * BK];   // 16 KB each
    __shared__ __align__(16) bf16 Bs[2][32 * BK];
    __shared__ f32x4 xacc[4][64];                   // 4 KB cross-wave combine
    __shared__ unsigned lastf;
    const int bid = blockIdx.x;
    const int mt = bid / ntiles, nt = bid % ntiles;
    const int tid = threadIdx.x, wave = tid >> 6, lane = tid & 63;
    const int g = wave >> 2, w2 = wave & 3;
    const int wm = w2 & 1, wn = w2 >> 1;
    const int lrow = lane & 15, quad = lane >> 4;

    const bf16* Ag = A  + (size_t)(mt * 32) * 1024;
    const bf16* Bg = Bt + (size_t)(nt * 32) * 1024;

    auto stage = [&](int buf, int kk) {
        const int k = kk * BK;
#pragma unroll
        for (int j = 0; j < 2; ++j) {
            int row0 = (wave + j * 8) * 2;             // wave-uniform; covers rows row0, row0+1
            int row = row0 + (lane >> 5);
            int ch  = (lane & 31) ^ (row & 31);        // swizzled source chunk (32 chunks/row)
            gload_lds16(Ag + (size_t)row * 1024 + k + ch * 8, &As[buf][row0 * BK]);
            gload_lds16(Bg + (size_t)row * 1024 + k + ch * 8, &Bs[buf][row0 * BK]);
        }
    };

    f32x4 acc = {};
    stage(0, 0);
    for (int kk = 0; kk < KITERS; ++kk) {
        const int cur = kk & 1;
        __syncthreads();
        if (kk + 1 < KITERS) stage(cur ^ 1, kk + 1);
#pragma unroll
        for (int ks = 0; ks < 4; ++ks) {
            int ra = wm * 16 + lrow, rb = wn * 16 + lrow;
            int c = g * 16 + ks * 4 + quad;            // group g takes its k-half
            bf16x8 af  = *(const bf16x8*)&As[cur][ra * BK + ((c ^ (ra & 31)) << 3)];
            bf16x8 bfr = *(const bf16x8*)&Bs[cur][rb * BK + ((c ^ (rb & 31)) << 3)];
            acc = __builtin_amdgcn_mfma_f32_16x16x32_bf16(af, bfr, acc, 0, 0, 0);
        }
    }
    // combine the two k-halves
    __syncthreads();
    if (g == 1) xacc[w2][lane] = acc;
    __syncthreads();
    if (g == 0) {
        f32x4 o = xacc[w2][lane];
        acc[0] += o[0]; acc[1] += o[1]; acc[2] += o[2]; acc[3] += o[3];
        int row0 = mt * 32 + wm * 16 + quad * 4;
        int col  = nt * 32 + wn * 16 + lrow;
        if (!LAST) {
            float bv = (col < Nreal) ? bias[col] : 0.f;
#pragma unroll
            for (int r = 0; r < 4; ++r)
                Ob[(size_t)(row0 + r) * 1024 + col] = (bf16)fmaxf(acc[r] + bv, 0.f);
        } else {
            bool valid = (col < 400);
            float bv = valid ? bias[col] : 0.f;
            float v[4];
#pragma unroll
            for (int r = 0; r < 4; ++r) v[r] = valid ? (acc[r] + bv) : 0.f;
            int p0 = row0 >> 1;                        // pairs p0, p0+1 (row0 even)
            float sums[6] = {v[0] * v[1], v[0] * v[0], v[1] * v[1],
                             v[2] * v[3], v[2] * v[2], v[3] * v[3]};
#pragma unroll
            for (int off = 1; off < 16; off <<= 1)
#pragma unroll
                for (int s = 0; s < 6; ++s) sums[s] += __shfl_xor(sums[s], off);
            if (lrow == 0) {
#pragma unroll
                for (int s = 0; s < 3; ++s) {
                    atomicAdd(&psums[(p0 + 0) * 3 + s], sums[s]);
                    atomicAdd(&psums[(p0 + 1) * 3 + s], sums[3 + s]);
                }
            }
        }
    }
    if (LAST) {
        // last-finisher cosine finalize: release our psum atomics, count arrivals;
        // block #224 acquires and computes the output (single block, no extra dispatch).
        __syncthreads();
        if (tid == 0) {
            __threadfence();               // release: psum atomics ordered before counter add
            unsigned old = __hip_atomic_fetch_add(done, 1u, __ATOMIC_ACQ_REL,
                                                  __HIP_MEMORY_SCOPE_AGENT);
            lastf = (old == 223u) ? 1u : 0u;
        }
        __syncthreads();
        if (lastf && tid < 256) {
            // agent-scope atomic loads bypass L1/L2 -> guaranteed-fresh psums
            float d  = __hip_atomic_load(&psums[tid * 3 + 0], __ATOMIC_RELAXED, __HIP_MEMORY_SCOPE_AGENT);
            float s1 = __hip_atomic_load(&psums[tid * 3 + 1], __ATOMIC_RELAXED, __HIP_MEMORY_SCOPE_AGENT);
            float s2 = __hip_atomic_load(&psums[tid * 3 + 2], __ATOMIC_RELAXED, __HIP_MEMORY_SCOPE_AGENT);
            float n1 = fmaxf(sqrtf(s1), 1e-6f);
            float n2 = fmaxf(sqrtf(s2), 1e-6f);
            out[tid] = d / (n1 * n2);
        }
    }
}

extern "C" void kernel_launch(void* const* d_in, const int* in_sizes, int n_in,
                              void* d_out, int out_size, void* d_ws, size_t ws_size,
                              hipStream_t stream) {
    const float* mz    = (const float*)d_in[0];
    const float* inten = (const float*)d_in[1];
    const float* bw    = (const float*)d_in[2];
    const float* bb    = (const float*)d_in[3];
    const float* w0    = (const float*)d_in[4];
    const float* b0    = (const float*)d_in[5];
    const float* w1    = (const float*)d_in[6];
    const float* b1    = (const float*)d_in[7];
    const float* w2    = (const float*)d_in[8];
    const float* b2    = (const float*)d_in[9];
    const float* we    = (const float*)d_in[10];
    const float* be    = (const float*)d_in[11];
    float* out = (float*)d_out;

    char* ws = (char*)d_ws;
    size_t off = 0;
    auto alloc = [&](size_t bytes) { char* p = ws + off; off += (bytes + 255) & ~(size_t)255; return p; };
    bf16*  A     = (bf16*) alloc((size_t)NSPEC * K0A * 2);
    bf16*  B0t   = (bf16*) alloc((size_t)N00 * K0A * 2);
    bf16*  B1t   = (bf16*) alloc((size_t)896 * 1024 * 2);
    bf16*  B2t   = (bf16*) alloc((size_t)896 * 1024 * 2);
    bf16*  BEt   = (bf16*) alloc((size_t)448 * 1024 * 2);
    bf16*  Cslab = (bf16*) alloc((size_t)KSPLIT0 * NSPEC * N00 * 2);   // 16 MB
    bf16*  H0b   = (bf16*) alloc((size_t)NSPEC * 1024 * 2);
    bf16*  H1b   = (bf16*) alloc((size_t)NSPEC * 1024 * 2);
    bf16*  H2b   = (bf16*) alloc((size_t)NSPEC * 1024 * 2);
    float* psums = (float*)alloc(1024 * 4);        // 768 psums + done counter + pad
    unsigned* done = (unsigned*)(psums + 768);

    // 1: weight transposes + build_A + zero pads + zero psums/done
    prep_all<<<6785, 512, 0, stream>>>(mz, inten, bw, bb, w0, w1, w2, we,
                                       A, B0t, B1t, B2t, BEt, H1b, H2b, psums);
    // 2: big GEMM, 128x128 tiles, split-K=16 XCD-pinned, swizzled LDS, bf16 slab stores
    gemm0_splitk<<<512, 512, 0, stream>>>(A, B0t, Cslab);
    // 3: slab reduce + bias + relu + bf16 cvt
    reduce_bias_relu<<<256, 256, 0, stream>>>(Cslab, b0, H0b);
    // 4-5: tail GEMMs, wave-split-K (bias+relu+bf16 fused)
    gemm_tail<false><<<448, 512, 0, stream>>>(H0b, B1t, b1, H1b, nullptr, nullptr, nullptr, 800, 28);
    gemm_tail<false><<<448, 512, 0, stream>>>(H1b, B2t, b2, H2b, nullptr, nullptr, nullptr, 800, 28);
    // 6: last GEMM + cosine partials + last-finisher finalize (cosine_fin dispatch dropped)
    gemm_tail<true ><<<224, 512, 0, stream>>>(H2b, BEt, be, nullptr, psums, done, out, 400, 14);
}

// Round 5
// 162.262 us; speedup vs baseline: 2.6051x; 1.0062x over previous
//
#include <hip/hip_runtime.h>

typedef __bf16 bf16;
typedef __bf16 bf16x8 __attribute__((ext_vector_type(8)));
typedef float  f32x4  __attribute__((ext_vector_type(4)));

// Problem constants
#define NSPEC   512          // 256 pairs * 2
#define BOUT    9999         // GROUPS*3
#define K0A     10240        // BOUT padded to 16*10*64 (ksplit*kiters*BK)
#define N00     1024         // 1000 padded
#define KSPLIT0 16

// async global->LDS, 16B per lane; lds base must be wave-uniform (HW adds lane*16)
__device__ __forceinline__ void gload_lds16(const bf16* g, bf16* l) {
    auto* gp = reinterpret_cast<const __attribute__((address_space(1))) unsigned int*>(
        reinterpret_cast<uintptr_t>(g));
    auto* lp = reinterpret_cast<__attribute__((address_space(3))) unsigned int*>(
        reinterpret_cast<uintptr_t>(l));
    __builtin_amdgcn_global_load_lds(gp, lp, 16, 0, 0);
}

// ---------------- transpose helper: 64(n) x 64(k) tile, 512 threads ----------------
// R5: 64x64 tiles (halves block count vs 64x32) + 16-B stores (128-B runs per n-row).
// tile is f32 [64][65] = 16.6 KB inside the caller's 40 KB smem.
__device__ __forceinline__ void transpose_tile64(const float* __restrict__ src,
                                                 bf16* __restrict__ dst,
                                                 int K, int N, int K0,
                                                 float* tile, int bx, int by) {
    int n0 = bx * 64, k0 = by * 64;
    int t = threadIdx.x;
    {
        int kr = t >> 3, fc = (t & 7) * 8;           // 64 k-rows x 64 n-cols, 8 f32/thread
        int gk = k0 + kr;
#pragma unroll
        for (int h = 0; h < 2; ++h) {
            int gn = n0 + fc + h * 4;
            float4 v;
            if (gk < K && gn + 3 < N) {              // interior fast path (N%4==0 -> aligned)
                v = *reinterpret_cast<const float4*>(src + (size_t)gk * N + gn);
            } else {
                v.x = (gk < K && gn + 0 < N) ? src[(size_t)gk * N + gn + 0] : 0.f;
                v.y = (gk < K && gn + 1 < N) ? src[(size_t)gk * N + gn + 1] : 0.f;
                v.z = (gk < K && gn + 2 < N) ? src[(size_t)gk * N + gn + 2] : 0.f;
                v.w = (gk < K && gn + 3 < N) ? src[(size_t)gk * N + gn + 3] : 0.f;
            }
            tile[kr * 65 + fc + h * 4 + 0] = v.x;
            tile[kr * 65 + fc + h * 4 + 1] = v.y;
            tile[kr * 65 + fc + h * 4 + 2] = v.z;
            tile[kr * 65 + fc + h * 4 + 3] = v.w;
        }
    }
    __syncthreads();
    {
        int nr = t >> 3, kc = (t & 7) * 8;           // 64 n-rows x 64 k-cols, 8 bf16/thread
        bf16 v[8];
#pragma unroll
        for (int e = 0; e < 8; ++e) v[e] = (bf16)tile[(kc + e) * 65 + nr];  // 2-way banks: free
        *(uint4*)&dst[(size_t)(n0 + nr) * K0 + k0 + kc] = *(uint4*)v;       // 16 B store
    }
}

// ---------------- mega-prep: weight transposes + build_A + zero pads + zero psums/done ----------------
// Block map (3665 blocks): w0 2560 | w1 224 | w2 224 | we 112 | build_A 512 | pads 32 | psums 1
__global__ __launch_bounds__(512) void prep_all(const float* __restrict__ mz,
                                                const float* __restrict__ inten,
                                                const float* __restrict__ bw,
                                                const float* __restrict__ bb,
                                                const float* __restrict__ w0,
                                                const float* __restrict__ w1,
                                                const float* __restrict__ w2,
                                                const float* __restrict__ we,
                                                bf16* __restrict__ A,
                                                bf16* __restrict__ B0t,
                                                bf16* __restrict__ B1t,
                                                bf16* __restrict__ B2t,
                                                bf16* __restrict__ BEt,
                                                bf16* __restrict__ H1b,
                                                bf16* __restrict__ H2b,
                                                float* __restrict__ psums) {
    __shared__ float smem[K0A];    // 40 KB: sacc for build_A, tile[64*65] for transposes
    int b = blockIdx.x;
    if (b < 2560) {                       // w0 -> B0t (1024 x 10240): 16(n) x 160(k) tiles
        transpose_tile64(w0, B0t, BOUT, 1000, K0A, smem, b & 15, b >> 4);
    } else if (b < 2784) {                // w1 -> B1t (896 x 1024): 14 x 16
        int r = b - 2560;
        transpose_tile64(w1, B1t, 1000, 800, 1024, smem, r % 14, r / 14);
    } else if (b < 3008) {                // w2 -> B2t (896 x 1024): 14 x 16
        int r = b - 2784;
        transpose_tile64(w2, B2t, 800, 800, 1024, smem, r % 14, r / 14);
    } else if (b < 3120) {                // we -> BEt (448 x 1024): 7 x 16
        int r = b - 3008;
        transpose_tile64(we, BEt, 800, 400, 1024, smem, r % 7, r / 7);
    } else if (b < 3632) {                // build_A: one block per spectrum
        const int spec = b - 3120;
        const int t = threadIdx.x;
#pragma unroll
        for (int i = 0; i < 5; ++i)
            *(float4*)&smem[(i * 512 + t) * 4] = float4{0.f, 0.f, 0.f, 0.f};
        __syncthreads();
        {
            float m = mz[(size_t)spec * 512 + t];
            float v = inten[(size_t)spec * 512 + t];
            bool mask = (m >= 0.0f) && (m < 1000.0f);
            int idx = (int)(m / 0.01f);       // IEEE div + trunc, matches astype(int32)
            idx = min(max(idx, 0), 99999);
            if (mask && idx < 99990) {
                int g = idx / 30;
                float val = sqrtf(v);         // inten ** 0.5
                const float* w = bw + (size_t)idx * 3;
                atomicAdd(&smem[g * 3 + 0], val * w[0]);
                atomicAdd(&smem[g * 3 + 1], val * w[1]);
                atomicAdd(&smem[g * 3 + 2], val * w[2]);
            }
        }
        __syncthreads();
        bf16* Arow = A + (size_t)spec * K0A;
#pragma unroll
        for (int i = 0; i < 5; ++i) {
            int c = (i * 512 + t) * 4;
            float4 s = *(const float4*)&smem[c];
            bf16 o[4];
            o[0] = (bf16)((c + 0 < BOUT) ? bb[c + 0] + s.x : 0.f);
            o[1] = (bf16)((c + 1 < BOUT) ? bb[c + 1] + s.y : 0.f);
            o[2] = (bf16)((c + 2 < BOUT) ? bb[c + 2] + s.z : 0.f);
            o[3] = (bf16)((c + 3 < BOUT) ? bb[c + 3] + s.w : 0.f);
            *(ushort4*)&Arow[c] = *(ushort4*)o;
        }
    } else if (b < 3664) {                // zero K-pad cols 896..1023 of H1b/H2b
        int idx = b - 3632;               // 0..31
        bf16* H = (idx < 16) ? H1b : H2b;
        int sub = idx & 15;
        int t = threadIdx.x;
        int row = sub * 32 + (t >> 4);
        int col = 896 + (t & 15) * 8;
        *(uint4*)&H[(size_t)row * 1024 + col] = uint4{0u, 0u, 0u, 0u};
    } else {                              // zero cosine accumulators + done counter
        for (int i = threadIdx.x; i < 1024; i += 512) psums[i] = 0.f;
    }
}

// ---------------- GEMM0: 128x128xBK64, 512 thr, split-K=16 XCD-pinned, dbuf, swizzled, bf16 slabs ----
__global__ __launch_bounds__(512) void gemm0_splitk(const bf16* __restrict__ A,
                                                    const bf16* __restrict__ Bt,
                                                    bf16* __restrict__ Cslab) {
    constexpr int K0 = K0A, KITERS = 10, BK = 64;
    __shared__ __align__(16) bf16 As[2][128 * BK];   // 16 KB each buf
    __shared__ __align__(16) bf16 Bs[2][128 * BK];   // 16 KB each buf
    const int bid = blockIdx.x;
    const int kp = bid & 15;                  // XCD = bid%8 hosts kp, kp+8 -> ~3.8 MB L2 footprint
    const int tile = bid >> 4;                // 0..31
    const int mt = tile & 3, nt = tile >> 2;  // 4 x 8
    const int tid = threadIdx.x, wave = tid >> 6, lane = tid & 63;
    const int wm = wave & 1, wn = wave >> 1;  // 2x4 wave grid: 64m x 32n per wave
    const int lrow = lane & 15, quad = lane >> 4;

    const bf16* Ag = A  + (size_t)(mt * 128) * K0 + kp * (KITERS * BK);
    const bf16* Bg = Bt + (size_t)(nt * 128) * K0 + kp * (KITERS * BK);

    auto stage = [&](int buf, int kk) {
        const int k = kk * BK;
        const int lr = lane >> 3;                      // lane's row within an 8-row group
        const int lch = lane & 7;
#pragma unroll
        for (int j = 0; j < 2; ++j) {                  // A: 128 rows in 2 calls/wave (8 rows/call)
            int row0 = j * 64 + wave * 8;
            int row = row0 + lr;
            int ch  = lch ^ (row & 7);
            gload_lds16(Ag + (size_t)row * K0 + k + ch * 8, &As[buf][row0 * BK]);
        }
#pragma unroll
        for (int j = 0; j < 2; ++j) {                  // B: 128 rows in 2 calls/wave
            int row0 = j * 64 + wave * 8;
            int row = row0 + lr;
            int ch  = lch ^ (row & 7);
            gload_lds16(Bg + (size_t)row * K0 + k + ch * 8, &Bs[buf][row0 * BK]);
        }
    };

    f32x4 acc[4][2] = {};
    stage(0, 0);
    for (int kk = 0; kk < KITERS; ++kk) {
        const int cur = kk & 1;
        __syncthreads();                      // buf[cur] drained (vmcnt0 at barrier)
        if (kk + 1 < KITERS) stage(cur ^ 1, kk + 1);  // prefetch overlaps compute
#pragma unroll
        for (int ks = 0; ks < 2; ++ks) {
            bf16x8 af[4], bfr[2];
            const int c = ks * 4 + quad;
#pragma unroll
            for (int im = 0; im < 4; ++im) {
                int r = wm * 64 + im * 16 + lrow;
                af[im] = *(const bf16x8*)&As[cur][r * BK + ((c ^ (r & 7)) << 3)];
            }
#pragma unroll
            for (int in = 0; in < 2; ++in) {
                int r = wn * 32 + in * 16 + lrow;
                bfr[in] = *(const bf16x8*)&Bs[cur][r * BK + ((c ^ (r & 7)) << 3)];
            }
#pragma unroll
            for (int im = 0; im < 4; ++im)
#pragma unroll
                for (int in = 0; in < 2; ++in)
                    acc[im][in] = __builtin_amdgcn_mfma_f32_16x16x32_bf16(af[im], bfr[in], acc[im][in], 0, 0, 0);
        }
    }
    // bf16 partial stores into this kp's slab — no atomics, no fences
    bf16* C = Cslab + (size_t)kp * (NSPEC * N00);
#pragma unroll
    for (int im = 0; im < 4; ++im) {
        int row0 = mt * 128 + wm * 64 + im * 16 + quad * 4;
#pragma unroll
        for (int in = 0; in < 2; ++in) {
            int col = nt * 128 + wn * 32 + in * 16 + lrow;
#pragma unroll
            for (int r = 0; r < 4; ++r)
                C[(size_t)(row0 + r) * N00 + col] = (bf16)acc[im][in][r];
        }
    }
}

// ---------------- reduce 16 bf16 slabs + bias + relu + bf16 cvt ----------------
__global__ __launch_bounds__(256) void reduce_bias_relu(const bf16* __restrict__ Cslab,
                                                        const float* __restrict__ b0,
                                                        bf16* __restrict__ H0b) {
    int idx = blockIdx.x * 256 + threadIdx.x;     // 65536 chunks of 8
    int r = idx >> 7, c = (idx & 127) * 8;
    float s[8] = {};
#pragma unroll
    for (int kp = 0; kp < KSPLIT0; ++kp) {
        bf16x8 v = *(const bf16x8*)&Cslab[(size_t)kp * (NSPEC * N00) + (size_t)r * N00 + c];
#pragma unroll
        for (int j = 0; j < 8; ++j) s[j] += (float)v[j];
    }
    bf16 o[8];
#pragma unroll
    for (int j = 0; j < 8; ++j)
        o[j] = (bf16)fmaxf(s[j] + ((c + j < 1000) ? b0[c + j] : 0.f), 0.f);
    *(uint4*)&H0b[(size_t)r * N00 + c] = *(uint4*)o;
}

// ---------------- tail GEMM: 32x64 tiles, 512 thr, BK=256, full-K per wave, dbuf, swizzled ----
// R5 rewrite: each of 8 waves (2m x 4n) owns one 16x16 quadrant with the FULL K range:
// 8 MFMA per K-iter per wave (was 4 + cross-wave combine). No g-split, no xacc, 2 fewer
// barriers. LDS 96 KB -> 1 block/CU. Grids: tail1/2 = 16x14 = 224, tail3 = 16x7 = 112.
// LAST=true finalizes cosine via done-counter (last of 112 blocks computes out[]).
template <bool LAST>
__global__ __launch_bounds__(512) void gemm_tail(const bf16* __restrict__ A,
                                                 const bf16* __restrict__ Bt,
                                                 const float* __restrict__ bias,
                                                 bf16* __restrict__ Ob,
                                                 float* __restrict__ psums,
                                                 unsigned* __restrict__ done,
                                                 float* __restrict__ out,
                                                 int Nreal, int ntiles) {
    constexpr int BK = 256, KITERS = 4;
    __shared__ __align__(16) bf16 As[2][32 * BK];   // 16 KB each
    __shared__ __align__(16) bf16 Bs[2][64 * BK];   // 32 KB each
    __shared__ unsigned lastf;
    const int bid = blockIdx.x;
    const int mt = bid / ntiles, nt = bid % ntiles;
    const int tid = threadIdx.x, wave = tid >> 6, lane = tid & 63;
    const int wm = wave & 1, wn = wave >> 1;        // 2(m) x 4(n) waves over 32x64
    const int lrow = lane & 15, quad = lane >> 4;

    const bf16* Ag = A  + (size_t)(mt * 32) * 1024;
    const bf16* Bg = Bt + (size_t)(nt * 64) * 1024;

    auto stage = [&](int buf, int kk) {
        const int k = kk * BK;
#pragma unroll
        for (int j = 0; j < 2; ++j) {                  // A: 32 rows, 2 calls/wave (2 rows/call)
            int row0 = (wave + j * 8) * 2;
            int row = row0 + (lane >> 5);
            int ch  = (lane & 31) ^ (row & 31);        // swizzled source chunk (32 chunks/row)
            gload_lds16(Ag + (size_t)row * 1024 + k + ch * 8, &As[buf][row0 * BK]);
        }
#pragma unroll
        for (int j = 0; j < 4; ++j) {                  // B: 64 rows, 4 calls/wave
            int row0 = (wave + j * 8) * 2;
            int row = row0 + (lane >> 5);
            int ch  = (lane & 31) ^ (row & 31);
            gload_lds16(Bg + (size_t)row * 1024 + k + ch * 8, &Bs[buf][row0 * BK]);
        }
    };

    f32x4 acc = {};
    stage(0, 0);
    for (int kk = 0; kk < KITERS; ++kk) {
        const int cur = kk & 1;
        __syncthreads();
        if (kk + 1 < KITERS) stage(cur ^ 1, kk + 1);
#pragma unroll
        for (int ks = 0; ks < 8; ++ks) {               // full K: 8 MFMA per iter per wave
            int ra = wm * 16 + lrow, rb = wn * 16 + lrow;
            int c = ks * 4 + quad;                     // c 0..31 covers BK=256
            bf16x8 af  = *(const bf16x8*)&As[cur][ra * BK + ((c ^ (ra & 31)) << 3)];
            bf16x8 bfr = *(const bf16x8*)&Bs[cur][rb * BK + ((c ^ (rb & 31)) << 3)];
            acc = __builtin_amdgcn_mfma_f32_16x16x32_bf16(af, bfr, acc, 0, 0, 0);
        }
    }
    // epilogue: each wave owns quadrant (wm, wn) — exactly-once coverage of 32x64
    {
        int row0 = mt * 32 + wm * 16 + quad * 4;
        int col  = nt * 64 + wn * 16 + lrow;
        if (!LAST) {
            float bv = (col < Nreal) ? bias[col] : 0.f;
#pragma unroll
            for (int r = 0; r < 4; ++r)
                Ob[(size_t)(row0 + r) * 1024 + col] = (bf16)fmaxf(acc[r] + bv, 0.f);
        } else {
            bool valid = (col < 400);
            float bv = valid ? bias[col] : 0.f;
            float v[4];
#pragma unroll
            for (int r = 0; r < 4; ++r) v[r] = valid ? (acc[r] + bv) : 0.f;
            int p0 = row0 >> 1;                        // pairs p0, p0+1 (row0 even)
            float sums[6] = {v[0] * v[1], v[0] * v[0], v[1] * v[1],
                             v[2] * v[3], v[2] * v[2], v[3] * v[3]};
#pragma unroll
            for (int off = 1; off < 16; off <<= 1)
#pragma unroll
                for (int s = 0; s < 6; ++s) sums[s] += __shfl_xor(sums[s], off);
            if (lrow == 0) {
#pragma unroll
                for (int s = 0; s < 3; ++s) {
                    atomicAdd(&psums[(p0 + 0) * 3 + s], sums[s]);
                    atomicAdd(&psums[(p0 + 1) * 3 + s], sums[3 + s]);
                }
            }
        }
    }
    if (LAST) {
        // last-finisher cosine finalize (112 blocks)
        __syncthreads();
        if (tid == 0) {
            __threadfence();               // release: psum atomics ordered before counter add
            unsigned old = __hip_atomic_fetch_add(done, 1u, __ATOMIC_ACQ_REL,
                                                  __HIP_MEMORY_SCOPE_AGENT);
            lastf = (old == 111u) ? 1u : 0u;
        }
        __syncthreads();
        if (lastf && tid < 256) {
            float d  = __hip_atomic_load(&psums[tid * 3 + 0], __ATOMIC_RELAXED, __HIP_MEMORY_SCOPE_AGENT);
            float s1 = __hip_atomic_load(&psums[tid * 3 + 1], __ATOMIC_RELAXED, __HIP_MEMORY_SCOPE_AGENT);
            float s2 = __hip_atomic_load(&psums[tid * 3 + 2], __ATOMIC_RELAXED, __HIP_MEMORY_SCOPE_AGENT);
            float n1 = fmaxf(sqrtf(s1), 1e-6f);
            float n2 = fmaxf(sqrtf(s2), 1e-6f);
            out[tid] = d / (n1 * n2);
        }
    }
}

extern "C" void kernel_launch(void* const* d_in, const int* in_sizes, int n_in,
                              void* d_out, int out_size, void* d_ws, size_t ws_size,
                              hipStream_t stream) {
    const float* mz    = (const float*)d_in[0];
    const float* inten = (const float*)d_in[1];
    const float* bw    = (const float*)d_in[2];
    const float* bb    = (const float*)d_in[3];
    const float* w0    = (const float*)d_in[4];
    const float* b0    = (const float*)d_in[5];
    const float* w1    = (const float*)d_in[6];
    const float* b1    = (const float*)d_in[7];
    const float* w2    = (const float*)d_in[8];
    const float* b2    = (const float*)d_in[9];
    const float* we    = (const float*)d_in[10];
    const float* be    = (const float*)d_in[11];
    float* out = (float*)d_out;

    char* ws = (char*)d_ws;
    size_t off = 0;
    auto alloc = [&](size_t bytes) { char* p = ws + off; off += (bytes + 255) & ~(size_t)255; return p; };
    bf16*  A     = (bf16*) alloc((size_t)NSPEC * K0A * 2);
    bf16*  B0t   = (bf16*) alloc((size_t)N00 * K0A * 2);
    bf16*  B1t   = (bf16*) alloc((size_t)896 * 1024 * 2);
    bf16*  B2t   = (bf16*) alloc((size_t)896 * 1024 * 2);
    bf16*  BEt   = (bf16*) alloc((size_t)448 * 1024 * 2);
    bf16*  Cslab = (bf16*) alloc((size_t)KSPLIT0 * NSPEC * N00 * 2);   // 16 MB
    bf16*  H0b   = (bf16*) alloc((size_t)NSPEC * 1024 * 2);
    bf16*  H1b   = (bf16*) alloc((size_t)NSPEC * 1024 * 2);
    bf16*  H2b   = (bf16*) alloc((size_t)NSPEC * 1024 * 2);
    float* psums = (float*)alloc(1024 * 4);        // 768 psums + done counter + pad
    unsigned* done = (unsigned*)(psums + 768);

    // 1: weight transposes (64x64 tiles) + build_A + zero pads + zero psums/done
    prep_all<<<3665, 512, 0, stream>>>(mz, inten, bw, bb, w0, w1, w2, we,
                                       A, B0t, B1t, B2t, BEt, H1b, H2b, psums);
    // 2: big GEMM, 128x128 tiles, split-K=16 XCD-pinned, swizzled LDS, bf16 slab stores
    gemm0_splitk<<<512, 512, 0, stream>>>(A, B0t, Cslab);
    // 3: slab reduce + bias + relu + bf16 cvt
    reduce_bias_relu<<<256, 256, 0, stream>>>(Cslab, b0, H0b);
    // 4-5: tail GEMMs, 32x64 tiles, full-K waves (bias+relu+bf16 fused)
    gemm_tail<false><<<224, 512, 0, stream>>>(H0b, B1t, b1, H1b, nullptr, nullptr, nullptr, 800, 14);
    gemm_tail<false><<<224, 512, 0, stream>>>(H1b, B2t, b2, H2b, nullptr, nullptr, nullptr, 800, 14);
    // 6: last GEMM + cosine partials + last-finisher finalize
    gemm_tail<true ><<<112, 512, 0, stream>>>(H2b, BEt, be, nullptr, psums, done, out, 400, 7);
}